// Round 11
// baseline (305.553 us; speedup 1.0000x reference)
//
#include <hip/hip_runtime.h>
#include <math.h>
#include <stdint.h>

#define N_EMBED   2048
#define N_EXPERTS 64
#define TOP_K     8
#define NT        64            // tokens per block
#define KC        128           // k-chunk (fp32 screen)
#define NCH       (N_EMBED / KC)
#define THR       4e-4f         // 3x rigorous fp32 split-chain error bound (~1.3e-4)

// ---------- fp64 monotone key (proven rounds 2/4/6/8/9/10) ----------
__device__ __forceinline__ uint64_t mono_key(double v, int lane) {
    uint64_t u = (uint64_t)__double_as_longlong(v);
    u = (u >> 63) ? ~u : (u | 0x8000000000000000ULL);
    return (u & ~63ULL) | (uint64_t)(63 - lane);
}
__device__ __forceinline__ double key_val(uint64_t k) {
    uint64_t u = k & ~63ULL;
    u = (u >> 63) ? (u & 0x7FFFFFFFFFFFFFFFULL) : ~u;
    return __longlong_as_double((long long)u);
}
// ---------- fp32 monotone key (screen) ----------
__device__ __forceinline__ uint32_t mono32(float v) {
    uint32_t u = __float_as_uint(v);
    return (u >> 31) ? ~u : (u | 0x80000000u);
}
__device__ __forceinline__ float val32(uint32_t k) {
    uint32_t u = (k & 0x80000000u) ? (k & 0x7FFFFFFFu) : ~k;
    return __uint_as_float(u);
}

// exact fp64 top-8 + softmax + store for one token (whole wave participates)
__device__ __forceinline__ void topk8_write(double v, int lane, size_t gtok,
                                            float* __restrict__ out_router,
                                            float* __restrict__ out_idx) {
    uint64_t mykey = mono_key(v, lane);
    float pv[TOP_K]; int pi[TOP_K];
    double vtop0 = 0.0;
#pragma unroll
    for (int j = 0; j < TOP_K; ++j) {
        uint64_t k = mykey;
#pragma unroll
        for (int m = 32; m >= 1; m >>= 1) {
            uint64_t o = (uint64_t)__shfl_xor((unsigned long long)k, m);
            k = (o > k) ? o : k;
        }
        const int widx = 63 - (int)(k & 63);
        const double wv = key_val(k);
        if (j == 0) vtop0 = wv;
        pv[j] = __expf((float)(wv - vtop0));
        pi[j] = widx;
        if (lane == widx) mykey = 0;
    }
    float s = 0.f;
#pragma unroll
    for (int j = 0; j < TOP_K; ++j) s += pv[j];
    const float inv = 1.f / s;

    float r = 0.f;
#pragma unroll
    for (int j = 0; j < TOP_K; ++j) r = (lane == pi[j]) ? pv[j] * inv : r;
    out_router[gtok * N_EXPERTS + lane] = r;

    float iv = 0.f;
#pragma unroll
    for (int j = 0; j < TOP_K; ++j) iv = (lane == j) ? (float)pi[j] : iv;
    if (lane < TOP_K)
        out_idx[gtok * TOP_K + lane] = iv;
}

// ---- prep: fp32 combined weights, layout Wgf[eg][k][8] (scalar path) ----
__global__ void combine_w_kernel(const float* __restrict__ Wl,
                                 const float* __restrict__ Wn,
                                 float* __restrict__ Wgf) {
    int f = blockIdx.x * 256 + threadIdx.x;    // = e*2048 + k, row-major
    int k = f & (N_EMBED - 1);
    int e = f >> 11;
    double w = (double)Wl[f] + (double)Wn[f];
    Wgf[(((size_t)(e >> 3) * N_EMBED + k) << 3) + (e & 7)] = (float)w;
}

// ---- fused: fp32 screen + in-block fp64 repair of flagged tokens ----
#define XSI(b, t, k) xsf[(b) * (64 * 130) + (t) * 130 + (k)]

__global__ __launch_bounds__(1024, 1)
void fused_kernel(const float* __restrict__ x, const float* __restrict__ Wgf,
                  const float* __restrict__ Wl, const float* __restrict__ Wn,
                  const float* __restrict__ bl, const float* __restrict__ bn,
                  float* __restrict__ out, int n_tokens) {
    __shared__ float xsf[2 * 64 * 130];      // 66,560 B; reused for logits
    __shared__ int flg[NT];
    __shared__ unsigned long long fmask;
    __shared__ double dpart[16][64];         // 8,192 B  repair partials

    const int tid  = threadIdx.x;
    const int lane = tid & 63;               // token (compute), expert (epilogue)
    const int wave = tid >> 6;               // 0..15
    const int t0   = blockIdx.x * NT;

    const int wid_u = __builtin_amdgcn_readfirstlane(wave);
    const int eg    = wid_u & 7;             // experts [8eg, 8eg+8)
    const int h     = wid_u >> 3;            // K-half of each chunk
    const int hb    = h * 64;

    // staging: 16 threads per token, 8 consecutive k each
    const int stok = tid >> 4;
    const int sks  = (tid & 15) * 8;

    float accA[8], accB[8];
#pragma unroll
    for (int e = 0; e < 8; ++e) { accA[e] = 0.f; accB[e] = 0.f; }

    // prologue: prefetch chunk 0 and commit to buf 0
    float4 pf0, pf1;
    {
        const float* xp = x + (size_t)(t0 + stok) * N_EMBED + sks;
        pf0 = *reinterpret_cast<const float4*>(xp);
        pf1 = *reinterpret_cast<const float4*>(xp + 4);
        float2 w0, w1, w2, w3;
        w0.x = pf0.x; w0.y = pf0.y; w1.x = pf0.z; w1.y = pf0.w;
        w2.x = pf1.x; w2.y = pf1.y; w3.x = pf1.z; w3.y = pf1.w;
        *reinterpret_cast<float2*>(&XSI(0, stok, sks + 0)) = w0;
        *reinterpret_cast<float2*>(&XSI(0, stok, sks + 2)) = w1;
        *reinterpret_cast<float2*>(&XSI(0, stok, sks + 4)) = w2;
        *reinterpret_cast<float2*>(&XSI(0, stok, sks + 6)) = w3;
    }

    for (int c = 0; c < NCH; ++c) {
        const int buf = c & 1;
        __syncthreads();               // buf committed & other buf free

        if (c + 1 < NCH) {             // issue next chunk's loads early
            const float* xp = x + (size_t)(t0 + stok) * N_EMBED + (c + 1) * KC + sks;
            pf0 = *reinterpret_cast<const float4*>(xp);
            pf1 = *reinterpret_cast<const float4*>(xp + 4);
        }

        const float* wb = Wgf + ((size_t)eg * N_EMBED + (size_t)c * KC + hb) * 8;
#pragma unroll 4
        for (int i2 = 0; i2 < 16; ++i2) {
            const float2 xA = *reinterpret_cast<const float2*>(&XSI(buf, lane, hb + 4 * i2));
            const float2 xB = *reinterpret_cast<const float2*>(&XSI(buf, lane, hb + 4 * i2 + 2));
            const float* wA = wb + 32 * i2;
            const float* wB = wb + 32 * i2 + 16;
#pragma unroll
            for (int e = 0; e < 8; ++e) accA[e] = fmaf(xA.x, wA[e], accA[e]);
#pragma unroll
            for (int e = 0; e < 8; ++e) accA[e] = fmaf(xA.y, wA[8 + e], accA[e]);
#pragma unroll
            for (int e = 0; e < 8; ++e) accB[e] = fmaf(xB.x, wB[e], accB[e]);
#pragma unroll
            for (int e = 0; e < 8; ++e) accB[e] = fmaf(xB.y, wB[8 + e], accB[e]);
        }

        if (c + 1 < NCH) {             // commit next chunk into other buffer
            float2 w0, w1, w2, w3;
            w0.x = pf0.x; w0.y = pf0.y; w1.x = pf0.z; w1.y = pf0.w;
            w2.x = pf1.x; w2.y = pf1.y; w3.x = pf1.z; w3.y = pf1.w;
            *reinterpret_cast<float2*>(&XSI(buf ^ 1, stok, sks + 0)) = w0;
            *reinterpret_cast<float2*>(&XSI(buf ^ 1, stok, sks + 2)) = w1;
            *reinterpret_cast<float2*>(&XSI(buf ^ 1, stok, sks + 4)) = w2;
            *reinterpret_cast<float2*>(&XSI(buf ^ 1, stok, sks + 6)) = w3;
        }
    }
    __syncthreads();                   // x buffers free; reuse for logits

    // ---- combine K-halves + bias -> nz[token][expert] (fp32) ----
    float* nz   = xsf;                       // nz[t*65 + e] : 4160 floats
    float* part = xsf + 4160;                // part[(eg*64+t)*8 + e]

    if (h == 1) {
#pragma unroll
        for (int e = 0; e < 8; ++e)
            part[(eg * 64 + lane) * 8 + e] = accA[e] + accB[e];
    }
    __syncthreads();
    if (h == 0) {
#pragma unroll
        for (int e = 0; e < 8; ++e) {
            const int ex = eg * 8 + e;
            const float be = (float)((double)bl[ex] + (double)bn[ex]);
            nz[lane * 65 + ex] = (accA[e] + accB[e]) + part[(eg * 64 + lane) * 8 + e] + be;
        }
    }
    __syncthreads();

    // ---- per-token top-9, margin flag; write only unflagged tokens ----
    float* out_router = out;
    float* out_idx    = out + (size_t)n_tokens * N_EXPERTS;
    const int tb = wave * 4;

#pragma unroll
    for (int t = 0; t < 4; ++t) {
        const float v = nz[(tb + t) * 65 + lane];       // lane = expert
        uint32_t mykey = (mono32(v) & ~63u) | (uint32_t)(63 - lane);

        float pv[TOP_K]; int pi[TOP_K];
        float vtop = 0.f, vprev = 0.f, ming = 1e30f;
#pragma unroll
        for (int j = 0; j < 9; ++j) {
            uint32_t k = mykey;
#pragma unroll
            for (int m = 32; m >= 1; m >>= 1) {
                uint32_t o = (uint32_t)__shfl_xor((int)k, m);
                k = (o > k) ? o : k;
            }
            const int widx = 63 - (int)(k & 63);
            const float wv = val32(k);
            if (j == 0) vtop = wv;
            if (j > 0) ming = fminf(ming, vprev - wv);
            vprev = wv;
            if (j < TOP_K) {
                pv[j] = __expf(wv - vtop);
                pi[j] = widx;
                if (lane == widx) mykey = 0;            // remove winner
            }
        }
        const int flagged = (ming < THR) ? 1 : 0;       // wave-uniform
        if (lane == 0) flg[tb + t] = flagged;

        if (!flagged) {
            float s = 0.f;
#pragma unroll
            for (int j = 0; j < TOP_K; ++j) s += pv[j];
            const float inv = 1.f / s;

            float r = 0.f;
#pragma unroll
            for (int j = 0; j < TOP_K; ++j) r = (lane == pi[j]) ? pv[j] * inv : r;
            out_router[(size_t)(t0 + tb + t) * N_EXPERTS + lane] = r;

            float iv = 0.f;
#pragma unroll
            for (int j = 0; j < TOP_K; ++j) iv = (lane == j) ? (float)pi[j] : iv;
            if (lane < TOP_K)
                out_idx[(size_t)(t0 + tb + t) * TOP_K + lane] = iv;
        }
    }
    __syncthreads();

    // ---- in-block fp64 repair of flagged tokens (all 16 waves) ----
    if (wave == 0) {
        const uint64_t m = __ballot(flg[lane] != 0);
        if (lane == 0) fmask = m;
    }
    __syncthreads();
    uint64_t mm = fmask;
    if (mm != 0) {
        const double myb = (double)bl[lane] + (double)bn[lane];  // lane = expert
        while (mm) {
            const int ft = (int)__ffsll((unsigned long long)mm) - 1;
            mm &= mm - 1;
            // wave w owns k in [128w, 128w+128); lane = expert
            const float* xr  = x  + ((size_t)(t0 + ft) << 11) + (wave << 7);
            const float* wlp = Wl + ((size_t)lane << 11) + (wave << 7);
            const float* wnp = Wn + ((size_t)lane << 11) + (wave << 7);
            double a = 0.0, b = 0.0;
#pragma unroll 4
            for (int i = 0; i < 128; i += 4) {
                const float4 xv = *reinterpret_cast<const float4*>(xr + i);
                const float4 wa = *reinterpret_cast<const float4*>(wlp + i);
                const float4 wn4 = *reinterpret_cast<const float4*>(wnp + i);
                a = fma((double)xv.x, (double)wa.x + (double)wn4.x, a);
                b = fma((double)xv.y, (double)wa.y + (double)wn4.y, b);
                a = fma((double)xv.z, (double)wa.z + (double)wn4.z, a);
                b = fma((double)xv.w, (double)wa.w + (double)wn4.w, b);
            }
            dpart[wave][lane] = a + b;
            __syncthreads();
            if (wave == 0) {
                double v = myb;
#pragma unroll
                for (int w = 0; w < 16; ++w) v += dpart[w][lane];
                topk8_write(v, lane, (size_t)(t0 + ft), out_router, out_idx);
            }
            __syncthreads();
        }
    }
}

// ---- fallback: proven round-6 kernel (used only if ws too small) ----
__global__ __launch_bounds__(512, 4)
void noisy_topk_fallback(const float* __restrict__ x,
                         const float* __restrict__ Wl, const float* __restrict__ bl,
                         const float* __restrict__ Wn, const float* __restrict__ bn,
                         float* __restrict__ out, int n_tokens) {
    __shared__ double Wt[64][N_EXPERTS];
    __shared__ double xsd[32][64];

    const int tid  = threadIdx.x;
    const int lane = tid & 63;
    const int wave = tid >> 6;
    const int t0   = blockIdx.x * 32;
    const int tb   = wave * 4;

    const int se = tid >> 3;
    const int sk = (tid & 7) * 8;
    const int st = tid >> 4;
    const int sx = (tid & 15) * 4;

    double acc[4];
#pragma unroll
    for (int t = 0; t < 4; ++t) acc[t] = 0.0;

    const double myb = (double)bl[lane] + (double)bn[lane];

    for (int c = 0; c < N_EMBED / 64; ++c) {
        const int kc = c * 64;
        __syncthreads();
        const float* wlp = Wl + (size_t)se * N_EMBED + kc + sk;
        const float* wnp = Wn + (size_t)se * N_EMBED + kc + sk;
#pragma unroll
        for (int i = 0; i < 2; ++i) {
            const float4 a = *reinterpret_cast<const float4*>(wlp + 4 * i);
            const float4 b = *reinterpret_cast<const float4*>(wnp + 4 * i);
            Wt[sk + 4 * i + 0][se] = (double)a.x + (double)b.x;
            Wt[sk + 4 * i + 1][se] = (double)a.y + (double)b.y;
            Wt[sk + 4 * i + 2][se] = (double)a.z + (double)b.z;
            Wt[sk + 4 * i + 3][se] = (double)a.w + (double)b.w;
        }
        {
            const float* xp = x + (size_t)(t0 + st) * N_EMBED + kc + sx;
            const float4 a = *reinterpret_cast<const float4*>(xp);
            xsd[st][sx + 0] = (double)a.x;
            xsd[st][sx + 1] = (double)a.y;
            xsd[st][sx + 2] = (double)a.z;
            xsd[st][sx + 3] = (double)a.w;
        }
        __syncthreads();
#pragma unroll 4
        for (int kk = 0; kk < 64; kk += 4) {
            const double w0 = Wt[kk + 0][lane];
            const double w1 = Wt[kk + 1][lane];
            const double w2 = Wt[kk + 2][lane];
            const double w3 = Wt[kk + 3][lane];
#pragma unroll
            for (int t = 0; t < 4; ++t) {
                const double2 p = *reinterpret_cast<const double2*>(&xsd[tb + t][kk]);
                const double2 q = *reinterpret_cast<const double2*>(&xsd[tb + t][kk + 2]);
                acc[t] = fma(p.x, w0, acc[t]);
                acc[t] = fma(p.y, w1, acc[t]);
                acc[t] = fma(q.x, w2, acc[t]);
                acc[t] = fma(q.y, w3, acc[t]);
            }
        }
    }

    float* out_router = out;
    float* out_idx    = out + (size_t)n_tokens * N_EXPERTS;
#pragma unroll
    for (int t = 0; t < 4; ++t)
        topk8_write(acc[t] + myb, lane, (size_t)(t0 + tb + t), out_router, out_idx);
}

extern "C" void kernel_launch(void* const* d_in, const int* in_sizes, int n_in,
                              void* d_out, int out_size, void* d_ws, size_t ws_size,
                              hipStream_t stream) {
    const float* x  = (const float*)d_in[0];
    const float* Wl = (const float*)d_in[1];
    const float* bl = (const float*)d_in[2];
    const float* Wn = (const float*)d_in[3];
    const float* bn = (const float*)d_in[4];
    float* out = (float*)d_out;

    int n_tokens = in_sizes[0] / N_EMBED;              // 16384
    const size_t need = (size_t)N_EXPERTS * N_EMBED * sizeof(float);  // 512 KB

    if (ws_size >= need) {
        float* Wgf = (float*)d_ws;
        hipLaunchKernelGGL(combine_w_kernel, dim3((N_EXPERTS * N_EMBED) / 256),
                           dim3(256), 0, stream, Wl, Wn, Wgf);
        hipLaunchKernelGGL(fused_kernel, dim3(n_tokens / NT), dim3(1024), 0, stream,
                           x, Wgf, Wl, Wn, bl, bn, out, n_tokens);
    } else {
        hipLaunchKernelGGL(noisy_topk_fallback, dim3(n_tokens / 32), dim3(512), 0, stream,
                           x, Wl, bl, Wn, bn, out, n_tokens);
    }
}

// Round 12
// 284.953 us; speedup vs baseline: 1.0723x; 1.0723x over previous
//
#include <hip/hip_runtime.h>
#include <math.h>
#include <stdint.h>

#define N_EMBED   2048
#define N_EXPERTS 64
#define TOP_K     8
#define NT        64            // tokens per block (pass 1)
#define KC        128           // k-chunk (pass 1, fp32)
#define NCH       (N_EMBED / KC)
#define THR       4e-4f         // 3x the rigorous fp32 split-chain error bound (~1.3e-4)

// ---------- fp64 monotone key (proven rounds 2/4/6/8/9/10) ----------
__device__ __forceinline__ uint64_t mono_key(double v, int lane) {
    uint64_t u = (uint64_t)__double_as_longlong(v);
    u = (u >> 63) ? ~u : (u | 0x8000000000000000ULL);
    return (u & ~63ULL) | (uint64_t)(63 - lane);
}
__device__ __forceinline__ double key_val(uint64_t k) {
    uint64_t u = k & ~63ULL;
    u = (u >> 63) ? (u & 0x7FFFFFFFFFFFFFFFULL) : ~u;
    return __longlong_as_double((long long)u);
}
// ---------- fp32 monotone key (pass 1) ----------
__device__ __forceinline__ uint32_t mono32(float v) {
    uint32_t u = __float_as_uint(v);
    return (u >> 31) ? ~u : (u | 0x80000000u);
}
__device__ __forceinline__ float val32(uint32_t k) {
    uint32_t u = (k & 0x80000000u) ? (k & 0x7FFFFFFFu) : ~k;
    return __uint_as_float(u);
}

// exact fp64 top-8 + softmax + store for one token (whole wave participates)
__device__ __forceinline__ void topk8_write(double v, int lane, size_t gtok,
                                            float* __restrict__ out_router,
                                            float* __restrict__ out_idx) {
    uint64_t mykey = mono_key(v, lane);
    float pv[TOP_K]; int pi[TOP_K];
    double vtop0 = 0.0;
#pragma unroll
    for (int j = 0; j < TOP_K; ++j) {
        uint64_t k = mykey;
#pragma unroll
        for (int m = 32; m >= 1; m >>= 1) {
            uint64_t o = (uint64_t)__shfl_xor((unsigned long long)k, m);
            k = (o > k) ? o : k;
        }
        const int widx = 63 - (int)(k & 63);
        const double wv = key_val(k);
        if (j == 0) vtop0 = wv;
        pv[j] = __expf((float)(wv - vtop0));
        pi[j] = widx;
        if (lane == widx) mykey = 0;
    }
    float s = 0.f;
#pragma unroll
    for (int j = 0; j < TOP_K; ++j) s += pv[j];
    const float inv = 1.f / s;

    float r = 0.f;
#pragma unroll
    for (int j = 0; j < TOP_K; ++j) r = (lane == pi[j]) ? pv[j] * inv : r;
    out_router[gtok * N_EXPERTS + lane] = r;

    float iv = 0.f;
#pragma unroll
    for (int j = 0; j < TOP_K; ++j) iv = (lane == j) ? (float)pi[j] : iv;
    if (lane < TOP_K)
        out_idx[gtok * TOP_K + lane] = iv;
}

// ---- prep: Wrow fp64 [e][k] (pass2) + Wgf fp32 [eg][k][8] (pass1) ----
__global__ void combine_w_kernel(const float* __restrict__ Wl,
                                 const float* __restrict__ Wn,
                                 double* __restrict__ Wrow,
                                 float* __restrict__ Wgf) {
    int f = blockIdx.x * 256 + threadIdx.x;    // = e*2048 + k, row-major
    int k = f & (N_EMBED - 1);
    int e = f >> 11;
    double w = (double)Wl[f] + (double)Wn[f];
    Wrow[f] = w;
    Wgf[(((size_t)(e >> 3) * N_EMBED + k) << 3) + (e & 7)] = (float)w;
}

// ---- pass 1: fp32 screen (VERBATIM from round 10 — proven) ----
#define XSI(b, t, k) xsf[(b) * (64 * 130) + (t) * 130 + (k)]

__global__ __launch_bounds__(1024, 1)
void pass1_kernel(const float* __restrict__ x, const float* __restrict__ Wgf,
                  const float* __restrict__ bl, const float* __restrict__ bn,
                  float* __restrict__ out, uint32_t* __restrict__ flags,
                  int n_tokens) {
    __shared__ float xsf[2 * 64 * 130];    // 66,560 B; reused for partials+logits

    const int tid  = threadIdx.x;
    const int lane = tid & 63;             // token (compute), expert (epilogue)
    const int wave = tid >> 6;             // 0..15
    const int t0   = blockIdx.x * NT;

    const int wid_u = __builtin_amdgcn_readfirstlane(wave);
    const int eg    = wid_u & 7;           // experts [8eg, 8eg+8)
    const int h     = wid_u >> 3;          // K-half of each chunk
    const int hb    = h * 64;

    // staging: 16 threads per token, 8 consecutive k each
    const int stok = tid >> 4;
    const int sks  = (tid & 15) * 8;

    float accA[8], accB[8];
#pragma unroll
    for (int e = 0; e < 8; ++e) { accA[e] = 0.f; accB[e] = 0.f; }

    // prologue: prefetch chunk 0 and commit to buf 0
    float4 pf0, pf1;
    {
        const float* xp = x + (size_t)(t0 + stok) * N_EMBED + sks;
        pf0 = *reinterpret_cast<const float4*>(xp);
        pf1 = *reinterpret_cast<const float4*>(xp + 4);
        float2 w0, w1, w2, w3;
        w0.x = pf0.x; w0.y = pf0.y; w1.x = pf0.z; w1.y = pf0.w;
        w2.x = pf1.x; w2.y = pf1.y; w3.x = pf1.z; w3.y = pf1.w;
        *reinterpret_cast<float2*>(&XSI(0, stok, sks + 0)) = w0;
        *reinterpret_cast<float2*>(&XSI(0, stok, sks + 2)) = w1;
        *reinterpret_cast<float2*>(&XSI(0, stok, sks + 4)) = w2;
        *reinterpret_cast<float2*>(&XSI(0, stok, sks + 6)) = w3;
    }

    for (int c = 0; c < NCH; ++c) {
        const int buf = c & 1;
        __syncthreads();               // buf committed & other buf free

        // issue next chunk's global loads (land during compute)
        if (c + 1 < NCH) {
            const float* xp = x + (size_t)(t0 + stok) * N_EMBED + (c + 1) * KC + sks;
            pf0 = *reinterpret_cast<const float4*>(xp);
            pf1 = *reinterpret_cast<const float4*>(xp + 4);
        }

        // compute on buf: per 2k: 1 ds_read_b64 + scalar W + fma
        const float* wb = Wgf + ((size_t)eg * N_EMBED + (size_t)c * KC + hb) * 8;
#pragma unroll 4
        for (int i2 = 0; i2 < 16; ++i2) {
            const float2 xA = *reinterpret_cast<const float2*>(&XSI(buf, lane, hb + 4 * i2));
            const float2 xB = *reinterpret_cast<const float2*>(&XSI(buf, lane, hb + 4 * i2 + 2));
            const float* wA = wb + 32 * i2;
            const float* wB = wb + 32 * i2 + 16;
#pragma unroll
            for (int e = 0; e < 8; ++e) accA[e] = fmaf(xA.x, wA[e], accA[e]);
#pragma unroll
            for (int e = 0; e < 8; ++e) accA[e] = fmaf(xA.y, wA[8 + e], accA[e]);
#pragma unroll
            for (int e = 0; e < 8; ++e) accB[e] = fmaf(xB.x, wB[e], accB[e]);
#pragma unroll
            for (int e = 0; e < 8; ++e) accB[e] = fmaf(xB.y, wB[8 + e], accB[e]);
        }

        // commit next chunk into the other buffer (after compute)
        if (c + 1 < NCH) {
            float2 w0, w1, w2, w3;
            w0.x = pf0.x; w0.y = pf0.y; w1.x = pf0.z; w1.y = pf0.w;
            w2.x = pf1.x; w2.y = pf1.y; w3.x = pf1.z; w3.y = pf1.w;
            *reinterpret_cast<float2*>(&XSI(buf ^ 1, stok, sks + 0)) = w0;
            *reinterpret_cast<float2*>(&XSI(buf ^ 1, stok, sks + 2)) = w1;
            *reinterpret_cast<float2*>(&XSI(buf ^ 1, stok, sks + 4)) = w2;
            *reinterpret_cast<float2*>(&XSI(buf ^ 1, stok, sks + 6)) = w3;
        }
    }
    __syncthreads();                   // done with x buffers; reuse for logits

    // ---- combine K-halves + bias -> nz[token][expert] (fp32) ----
    float* nz   = xsf;                       // nz[t*65 + e] : 4160 floats
    float* part = xsf + 4160;                // part[(eg*64+t)*8 + e] : 4096 floats

    if (h == 1) {
#pragma unroll
        for (int e = 0; e < 8; ++e)
            part[(eg * 64 + lane) * 8 + e] = accA[e] + accB[e];
    }
    __syncthreads();
    if (h == 0) {
#pragma unroll
        for (int e = 0; e < 8; ++e) {
            const int ex = eg * 8 + e;
            const float be = (float)((double)bl[ex] + (double)bn[ex]);
            nz[lane * 65 + ex] = (accA[e] + accB[e]) + part[(eg * 64 + lane) * 8 + e] + be;
        }
    }
    __syncthreads();

    // ---- per-token top-9, margin flag, softmax, stores ----
    float* out_router = out;
    float* out_idx    = out + (size_t)n_tokens * N_EXPERTS;
    const int tb = wave * 4;

#pragma unroll
    for (int t = 0; t < 4; ++t) {
        const float v = nz[(tb + t) * 65 + lane];       // lane = expert
        uint32_t mykey = (mono32(v) & ~63u) | (uint32_t)(63 - lane);

        float pv[TOP_K]; int pi[TOP_K];
        float vtop = 0.f, vprev = 0.f, ming = 1e30f;
#pragma unroll
        for (int j = 0; j < 9; ++j) {
            uint32_t k = mykey;
#pragma unroll
            for (int m = 32; m >= 1; m >>= 1) {
                uint32_t o = (uint32_t)__shfl_xor((int)k, m);
                k = (o > k) ? o : k;
            }
            const int widx = 63 - (int)(k & 63);
            const float wv = val32(k);
            if (j == 0) vtop = wv;
            if (j > 0) ming = fminf(ming, vprev - wv);
            vprev = wv;
            if (j < TOP_K) {
                pv[j] = __expf(wv - vtop);
                pi[j] = widx;
                if (lane == widx) mykey = 0;            // remove winner
            }
        }
        float s = 0.f;
#pragma unroll
        for (int j = 0; j < TOP_K; ++j) s += pv[j];
        const float inv = 1.f / s;

        float r = 0.f;
#pragma unroll
        for (int j = 0; j < TOP_K; ++j) r = (lane == pi[j]) ? pv[j] * inv : r;
        out_router[(size_t)(t0 + tb + t) * N_EXPERTS + lane] = r;

        float iv = 0.f;
#pragma unroll
        for (int j = 0; j < TOP_K; ++j) iv = (lane == j) ? (float)pi[j] : iv;
        if (lane < TOP_K)
            out_idx[(size_t)(t0 + tb + t) * TOP_K + lane] = iv;

        if (lane == 0)
            flags[t0 + tb + t] = (ming < THR) ? 1u : 0u;
    }
}

// ---- pass 2: exact fp64 repair, ONE WAVE PER TOKEN (balanced, latency-hidden) ----
__global__ __launch_bounds__(256, 4)
void pass2_kernel(const float* __restrict__ x, const double* __restrict__ Wrow,
                  const float* __restrict__ bl, const float* __restrict__ bn,
                  const uint32_t* __restrict__ flags,
                  float* __restrict__ out, int n_tokens) {
    const int tid  = threadIdx.x;
    const int lane = tid & 63;               // expert
    const int wave = tid >> 6;               // 0..3
    const int t    = blockIdx.x * 4 + wave;  // one token per wave

    if (flags[t] == 0) return;               // wave-uniform fast exit

    const double* wrow = Wrow + ((size_t)lane << 11);   // my expert's fp64 row
    const float*  xr   = x + ((size_t)t << 11);         // wave-uniform x row

    double a0 = 0.0, a1 = 0.0, a2 = 0.0, a3 = 0.0;
#pragma unroll 4
    for (int i = 0; i < N_EMBED; i += 8) {
        const double2 w0 = *reinterpret_cast<const double2*>(wrow + i);
        const double2 w1 = *reinterpret_cast<const double2*>(wrow + i + 2);
        const double2 w2 = *reinterpret_cast<const double2*>(wrow + i + 4);
        const double2 w3 = *reinterpret_cast<const double2*>(wrow + i + 6);
        const float4  p  = *reinterpret_cast<const float4*>(xr + i);
        const float4  q  = *reinterpret_cast<const float4*>(xr + i + 4);
        a0 = fma((double)p.x, w0.x, a0);
        a1 = fma((double)p.y, w0.y, a1);
        a2 = fma((double)p.z, w1.x, a2);
        a3 = fma((double)p.w, w1.y, a3);
        a0 = fma((double)q.x, w2.x, a0);
        a1 = fma((double)q.y, w2.y, a1);
        a2 = fma((double)q.z, w3.x, a2);
        a3 = fma((double)q.w, w3.y, a3);
    }
    const double myb = (double)bl[lane] + (double)bn[lane];
    const double v = ((a0 + a1) + (a2 + a3)) + myb;

    float* out_router = out;
    float* out_idx    = out + (size_t)n_tokens * N_EXPERTS;
    topk8_write(v, lane, (size_t)t, out_router, out_idx);
}

// ---- fallback: proven round-6 kernel (used only if ws too small) ----
__global__ __launch_bounds__(512, 4)
void noisy_topk_fallback(const float* __restrict__ x,
                         const float* __restrict__ Wl, const float* __restrict__ bl,
                         const float* __restrict__ Wn, const float* __restrict__ bn,
                         float* __restrict__ out, int n_tokens) {
    __shared__ double Wt[64][N_EXPERTS];
    __shared__ double xsd[32][64];

    const int tid  = threadIdx.x;
    const int lane = tid & 63;
    const int wave = tid >> 6;
    const int t0   = blockIdx.x * 32;
    const int tb   = wave * 4;

    const int se = tid >> 3;
    const int sk = (tid & 7) * 8;
    const int st = tid >> 4;
    const int sx = (tid & 15) * 4;

    double acc[4];
#pragma unroll
    for (int t = 0; t < 4; ++t) acc[t] = 0.0;

    const double myb = (double)bl[lane] + (double)bn[lane];

    for (int c = 0; c < N_EMBED / 64; ++c) {
        const int kc = c * 64;
        __syncthreads();
        const float* wlp = Wl + (size_t)se * N_EMBED + kc + sk;
        const float* wnp = Wn + (size_t)se * N_EMBED + kc + sk;
#pragma unroll
        for (int i = 0; i < 2; ++i) {
            const float4 a = *reinterpret_cast<const float4*>(wlp + 4 * i);
            const float4 b = *reinterpret_cast<const float4*>(wnp + 4 * i);
            Wt[sk + 4 * i + 0][se] = (double)a.x + (double)b.x;
            Wt[sk + 4 * i + 1][se] = (double)a.y + (double)b.y;
            Wt[sk + 4 * i + 2][se] = (double)a.z + (double)b.z;
            Wt[sk + 4 * i + 3][se] = (double)a.w + (double)b.w;
        }
        {
            const float* xp = x + (size_t)(t0 + st) * N_EMBED + kc + sx;
            const float4 a = *reinterpret_cast<const float4*>(xp);
            xsd[st][sx + 0] = (double)a.x;
            xsd[st][sx + 1] = (double)a.y;
            xsd[st][sx + 2] = (double)a.z;
            xsd[st][sx + 3] = (double)a.w;
        }
        __syncthreads();
#pragma unroll 4
        for (int kk = 0; kk < 64; kk += 4) {
            const double w0 = Wt[kk + 0][lane];
            const double w1 = Wt[kk + 1][lane];
            const double w2 = Wt[kk + 2][lane];
            const double w3 = Wt[kk + 3][lane];
#pragma unroll
            for (int t = 0; t < 4; ++t) {
                const double2 p = *reinterpret_cast<const double2*>(&xsd[tb + t][kk]);
                const double2 q = *reinterpret_cast<const double2*>(&xsd[tb + t][kk + 2]);
                acc[t] = fma(p.x, w0, acc[t]);
                acc[t] = fma(p.y, w1, acc[t]);
                acc[t] = fma(q.x, w2, acc[t]);
                acc[t] = fma(q.y, w3, acc[t]);
            }
        }
    }

    float* out_router = out;
    float* out_idx    = out + (size_t)n_tokens * N_EXPERTS;
#pragma unroll
    for (int t = 0; t < 4; ++t)
        topk8_write(acc[t] + myb, lane, (size_t)(t0 + tb + t), out_router, out_idx);
}

extern "C" void kernel_launch(void* const* d_in, const int* in_sizes, int n_in,
                              void* d_out, int out_size, void* d_ws, size_t ws_size,
                              hipStream_t stream) {
    const float* x  = (const float*)d_in[0];
    const float* Wl = (const float*)d_in[1];
    const float* bl = (const float*)d_in[2];
    const float* Wn = (const float*)d_in[3];
    const float* bn = (const float*)d_in[4];
    float* out = (float*)d_out;

    int n_tokens = in_sizes[0] / N_EMBED;              // 16384

    const size_t off_wgf   = (size_t)N_EXPERTS * N_EMBED * sizeof(double);  // 1 MB
    const size_t off_flags = off_wgf + (size_t)N_EXPERTS * N_EMBED * sizeof(float);
    const size_t need      = off_flags + (size_t)n_tokens * sizeof(uint32_t);

    if (ws_size >= need) {
        double*   Wrow  = (double*)d_ws;
        float*    Wgf   = (float*)((char*)d_ws + off_wgf);
        uint32_t* flags = (uint32_t*)((char*)d_ws + off_flags);

        hipLaunchKernelGGL(combine_w_kernel, dim3((N_EXPERTS * N_EMBED) / 256),
                           dim3(256), 0, stream, Wl, Wn, Wrow, Wgf);
        hipLaunchKernelGGL(pass1_kernel, dim3(n_tokens / NT), dim3(1024), 0, stream,
                           x, Wgf, bl, bn, out, flags, n_tokens);
        hipLaunchKernelGGL(pass2_kernel, dim3(n_tokens / 4), dim3(256), 0, stream,
                           x, Wrow, bl, bn, flags, out, n_tokens);
    } else {
        hipLaunchKernelGGL(noisy_topk_fallback, dim3(n_tokens / 32), dim3(512), 0, stream,
                           x, Wl, bl, Wn, bn, out, n_tokens);
    }
}

// Round 13
// 132.800 us; speedup vs baseline: 2.3008x; 2.1457x over previous
//
#include <hip/hip_runtime.h>
#include <math.h>
#include <stdint.h>

#define N_EMBED   2048
#define N_EXPERTS 64
#define TOP_K     8
#define NT        64            // tokens per block (pass 1)
#define KC        128           // k-chunk (pass 1, fp32)
#define NCH       (N_EMBED / KC)
#define THR       4e-4f         // 3x the rigorous fp32 split-chain error bound (~1.3e-4)

// ---------- fp64 monotone key (proven rounds 2/4/6/8-12) ----------
__device__ __forceinline__ uint64_t mono_key(double v, int lane) {
    uint64_t u = (uint64_t)__double_as_longlong(v);
    u = (u >> 63) ? ~u : (u | 0x8000000000000000ULL);
    return (u & ~63ULL) | (uint64_t)(63 - lane);
}
__device__ __forceinline__ double key_val(uint64_t k) {
    uint64_t u = k & ~63ULL;
    u = (u >> 63) ? (u & 0x7FFFFFFFFFFFFFFFULL) : ~u;
    return __longlong_as_double((long long)u);
}
// ---------- fp32 monotone key (pass 1) ----------
__device__ __forceinline__ uint32_t mono32(float v) {
    uint32_t u = __float_as_uint(v);
    return (u >> 31) ? ~u : (u | 0x80000000u);
}
__device__ __forceinline__ float val32(uint32_t k) {
    uint32_t u = (k & 0x80000000u) ? (k & 0x7FFFFFFFu) : ~k;
    return __uint_as_float(u);
}

// exact fp64 top-8 + softmax + store for one token (whole wave participates)
__device__ __forceinline__ void topk8_write(double v, int lane, size_t gtok,
                                            float* __restrict__ out_router,
                                            float* __restrict__ out_idx) {
    uint64_t mykey = mono_key(v, lane);
    float pv[TOP_K]; int pi[TOP_K];
    double vtop0 = 0.0;
#pragma unroll
    for (int j = 0; j < TOP_K; ++j) {
        uint64_t k = mykey;
#pragma unroll
        for (int m = 32; m >= 1; m >>= 1) {
            uint64_t o = (uint64_t)__shfl_xor((unsigned long long)k, m);
            k = (o > k) ? o : k;
        }
        const int widx = 63 - (int)(k & 63);
        const double wv = key_val(k);
        if (j == 0) vtop0 = wv;
        pv[j] = __expf((float)(wv - vtop0));
        pi[j] = widx;
        if (lane == widx) mykey = 0;
    }
    float s = 0.f;
#pragma unroll
    for (int j = 0; j < TOP_K; ++j) s += pv[j];
    const float inv = 1.f / s;

    float r = 0.f;
#pragma unroll
    for (int j = 0; j < TOP_K; ++j) r = (lane == pi[j]) ? pv[j] * inv : r;
    out_router[gtok * N_EXPERTS + lane] = r;

    float iv = 0.f;
#pragma unroll
    for (int j = 0; j < TOP_K; ++j) iv = (lane == j) ? (float)pi[j] : iv;
    if (lane < TOP_K)
        out_idx[gtok * TOP_K + lane] = iv;
}

// ---- prep: Wp fp64 k-major pairs [k/2][e][2] (pass2, coalesced) +
//            Wgf fp32 [eg][k][8] (pass1 scalar path) ----
__global__ void combine_w_kernel(const float* __restrict__ Wl,
                                 const float* __restrict__ Wn,
                                 double* __restrict__ Wp,
                                 float* __restrict__ Wgf) {
    int f = blockIdx.x * 256 + threadIdx.x;    // = e*2048 + k, row-major
    int k = f & (N_EMBED - 1);
    int e = f >> 11;
    double w = (double)Wl[f] + (double)Wn[f];
    Wp[(((size_t)(k >> 1) << 6) + e) * 2 + (k & 1)] = w;
    Wgf[(((size_t)(e >> 3) * N_EMBED + k) << 3) + (e & 7)] = (float)w;
}

// ---- pass 1: fp32 screen (VERBATIM — proven rounds 10/11/12) ----
#define XSI(b, t, k) xsf[(b) * (64 * 130) + (t) * 130 + (k)]

__global__ __launch_bounds__(1024, 1)
void pass1_kernel(const float* __restrict__ x, const float* __restrict__ Wgf,
                  const float* __restrict__ bl, const float* __restrict__ bn,
                  float* __restrict__ out, uint32_t* __restrict__ flags,
                  int n_tokens) {
    __shared__ float xsf[2 * 64 * 130];    // 66,560 B; reused for partials+logits

    const int tid  = threadIdx.x;
    const int lane = tid & 63;             // token (compute), expert (epilogue)
    const int wave = tid >> 6;             // 0..15
    const int t0   = blockIdx.x * NT;

    const int wid_u = __builtin_amdgcn_readfirstlane(wave);
    const int eg    = wid_u & 7;           // experts [8eg, 8eg+8)
    const int h     = wid_u >> 3;          // K-half of each chunk
    const int hb    = h * 64;

    // staging: 16 threads per token, 8 consecutive k each
    const int stok = tid >> 4;
    const int sks  = (tid & 15) * 8;

    float accA[8], accB[8];
#pragma unroll
    for (int e = 0; e < 8; ++e) { accA[e] = 0.f; accB[e] = 0.f; }

    // prologue: prefetch chunk 0 and commit to buf 0
    float4 pf0, pf1;
    {
        const float* xp = x + (size_t)(t0 + stok) * N_EMBED + sks;
        pf0 = *reinterpret_cast<const float4*>(xp);
        pf1 = *reinterpret_cast<const float4*>(xp + 4);
        float2 w0, w1, w2, w3;
        w0.x = pf0.x; w0.y = pf0.y; w1.x = pf0.z; w1.y = pf0.w;
        w2.x = pf1.x; w2.y = pf1.y; w3.x = pf1.z; w3.y = pf1.w;
        *reinterpret_cast<float2*>(&XSI(0, stok, sks + 0)) = w0;
        *reinterpret_cast<float2*>(&XSI(0, stok, sks + 2)) = w1;
        *reinterpret_cast<float2*>(&XSI(0, stok, sks + 4)) = w2;
        *reinterpret_cast<float2*>(&XSI(0, stok, sks + 6)) = w3;
    }

    for (int c = 0; c < NCH; ++c) {
        const int buf = c & 1;
        __syncthreads();               // buf committed & other buf free

        // issue next chunk's global loads (land during compute)
        if (c + 1 < NCH) {
            const float* xp = x + (size_t)(t0 + stok) * N_EMBED + (c + 1) * KC + sks;
            pf0 = *reinterpret_cast<const float4*>(xp);
            pf1 = *reinterpret_cast<const float4*>(xp + 4);
        }

        // compute on buf: per 2k: 1 ds_read_b64 + scalar W + fma
        const float* wb = Wgf + ((size_t)eg * N_EMBED + (size_t)c * KC + hb) * 8;
#pragma unroll 4
        for (int i2 = 0; i2 < 16; ++i2) {
            const float2 xA = *reinterpret_cast<const float2*>(&XSI(buf, lane, hb + 4 * i2));
            const float2 xB = *reinterpret_cast<const float2*>(&XSI(buf, lane, hb + 4 * i2 + 2));
            const float* wA = wb + 32 * i2;
            const float* wB = wb + 32 * i2 + 16;
#pragma unroll
            for (int e = 0; e < 8; ++e) accA[e] = fmaf(xA.x, wA[e], accA[e]);
#pragma unroll
            for (int e = 0; e < 8; ++e) accA[e] = fmaf(xA.y, wA[8 + e], accA[e]);
#pragma unroll
            for (int e = 0; e < 8; ++e) accB[e] = fmaf(xB.x, wB[e], accB[e]);
#pragma unroll
            for (int e = 0; e < 8; ++e) accB[e] = fmaf(xB.y, wB[8 + e], accB[e]);
        }

        // commit next chunk into the other buffer (after compute)
        if (c + 1 < NCH) {
            float2 w0, w1, w2, w3;
            w0.x = pf0.x; w0.y = pf0.y; w1.x = pf0.z; w1.y = pf0.w;
            w2.x = pf1.x; w2.y = pf1.y; w3.x = pf1.z; w3.y = pf1.w;
            *reinterpret_cast<float2*>(&XSI(buf ^ 1, stok, sks + 0)) = w0;
            *reinterpret_cast<float2*>(&XSI(buf ^ 1, stok, sks + 2)) = w1;
            *reinterpret_cast<float2*>(&XSI(buf ^ 1, stok, sks + 4)) = w2;
            *reinterpret_cast<float2*>(&XSI(buf ^ 1, stok, sks + 6)) = w3;
        }
    }
    __syncthreads();                   // done with x buffers; reuse for logits

    // ---- combine K-halves + bias -> nz[token][expert] (fp32) ----
    float* nz   = xsf;                       // nz[t*65 + e] : 4160 floats
    float* part = xsf + 4160;                // part[(eg*64+t)*8 + e] : 4096 floats

    if (h == 1) {
#pragma unroll
        for (int e = 0; e < 8; ++e)
            part[(eg * 64 + lane) * 8 + e] = accA[e] + accB[e];
    }
    __syncthreads();
    if (h == 0) {
#pragma unroll
        for (int e = 0; e < 8; ++e) {
            const int ex = eg * 8 + e;
            const float be = (float)((double)bl[ex] + (double)bn[ex]);
            nz[lane * 65 + ex] = (accA[e] + accB[e]) + part[(eg * 64 + lane) * 8 + e] + be;
        }
    }
    __syncthreads();

    // ---- per-token top-9, margin flag, softmax, stores ----
    float* out_router = out;
    float* out_idx    = out + (size_t)n_tokens * N_EXPERTS;
    const int tb = wave * 4;

#pragma unroll
    for (int t = 0; t < 4; ++t) {
        const float v = nz[(tb + t) * 65 + lane];       // lane = expert
        uint32_t mykey = (mono32(v) & ~63u) | (uint32_t)(63 - lane);

        float pv[TOP_K]; int pi[TOP_K];
        float vtop = 0.f, vprev = 0.f, ming = 1e30f;
#pragma unroll
        for (int j = 0; j < 9; ++j) {
            uint32_t k = mykey;
#pragma unroll
            for (int m = 32; m >= 1; m >>= 1) {
                uint32_t o = (uint32_t)__shfl_xor((int)k, m);
                k = (o > k) ? o : k;
            }
            const int widx = 63 - (int)(k & 63);
            const float wv = val32(k);
            if (j == 0) vtop = wv;
            if (j > 0) ming = fminf(ming, vprev - wv);
            vprev = wv;
            if (j < TOP_K) {
                pv[j] = __expf(wv - vtop);
                pi[j] = widx;
                if (lane == widx) mykey = 0;            // remove winner
            }
        }
        float s = 0.f;
#pragma unroll
        for (int j = 0; j < TOP_K; ++j) s += pv[j];
        const float inv = 1.f / s;

        float r = 0.f;
#pragma unroll
        for (int j = 0; j < TOP_K; ++j) r = (lane == pi[j]) ? pv[j] * inv : r;
        out_router[(size_t)(t0 + tb + t) * N_EXPERTS + lane] = r;

        float iv = 0.f;
#pragma unroll
        for (int j = 0; j < TOP_K; ++j) iv = (lane == j) ? (float)pi[j] : iv;
        if (lane < TOP_K)
            out_idx[(size_t)(t0 + tb + t) * TOP_K + lane] = iv;

        if (lane == 0)
            flags[t0 + tb + t] = (ming < THR) ? 1u : 0u;
    }
}

// ---- pass 2: exact fp64 repair, BLOCK PER TOKEN, coalesced k-major W ----
__global__ __launch_bounds__(256, 4)
void pass2_kernel(const float* __restrict__ x, const double* __restrict__ Wp,
                  const float* __restrict__ bl, const float* __restrict__ bn,
                  const uint32_t* __restrict__ flags,
                  float* __restrict__ out, int n_tokens) {
    __shared__ float  xls[N_EMBED];          // 8 KB x row
    __shared__ double dpart[4][N_EXPERTS];   // 2 KB partials

    const int tid  = threadIdx.x;
    const int lane = tid & 63;               // expert
    const int wave = tid >> 6;               // 0..3 (k-quarter)
    const int t    = blockIdx.x;

    if (flags[t] == 0) return;               // block-uniform fast exit

    // stage x row (coalesced, 8 floats/thread)
    {
        const float* xr = x + ((size_t)t << 11) + tid * 8;
        const float4 a = *reinterpret_cast<const float4*>(xr);
        const float4 b = *reinterpret_cast<const float4*>(xr + 4);
        *reinterpret_cast<float4*>(&xls[tid * 8])     = a;
        *reinterpret_cast<float4*>(&xls[tid * 8 + 4]) = b;
    }
    __syncthreads();

    // wave w owns k-pairs [256w, 256w+256); lane = expert, coalesced W loads
    double acc = 0.0;
    const double* wq = Wp + (((size_t)wave << 8) * 64 + lane) * 2;
#pragma unroll 4
    for (int i = 0; i < 256; ++i) {
        const float2  xf = *reinterpret_cast<const float2*>(&xls[(wave << 9) + 2 * i]);
        const double2 wp = *reinterpret_cast<const double2*>(wq + (size_t)i * 128);
        acc = fma((double)xf.x, wp.x, acc);
        acc = fma((double)xf.y, wp.y, acc);
    }
    dpart[wave][lane] = acc;
    __syncthreads();

    if (wave == 0) {
        const double myb = (double)bl[lane] + (double)bn[lane];
        double v = myb + dpart[0][lane] + dpart[1][lane] + dpart[2][lane] + dpart[3][lane];
        float* out_router = out;
        float* out_idx    = out + (size_t)n_tokens * N_EXPERTS;
        topk8_write(v, lane, (size_t)t, out_router, out_idx);
    }
}

// ---- fallback: proven round-6 kernel (used only if ws too small) ----
__global__ __launch_bounds__(512, 4)
void noisy_topk_fallback(const float* __restrict__ x,
                         const float* __restrict__ Wl, const float* __restrict__ bl,
                         const float* __restrict__ Wn, const float* __restrict__ bn,
                         float* __restrict__ out, int n_tokens) {
    __shared__ double Wt[64][N_EXPERTS];
    __shared__ double xsd[32][64];

    const int tid  = threadIdx.x;
    const int lane = tid & 63;
    const int wave = tid >> 6;
    const int t0   = blockIdx.x * 32;
    const int tb   = wave * 4;

    const int se = tid >> 3;
    const int sk = (tid & 7) * 8;
    const int st = tid >> 4;
    const int sx = (tid & 15) * 4;

    double acc[4];
#pragma unroll
    for (int t = 0; t < 4; ++t) acc[t] = 0.0;

    const double myb = (double)bl[lane] + (double)bn[lane];

    for (int c = 0; c < N_EMBED / 64; ++c) {
        const int kc = c * 64;
        __syncthreads();
        const float* wlp = Wl + (size_t)se * N_EMBED + kc + sk;
        const float* wnp = Wn + (size_t)se * N_EMBED + kc + sk;
#pragma unroll
        for (int i = 0; i < 2; ++i) {
            const float4 a = *reinterpret_cast<const float4*>(wlp + 4 * i);
            const float4 b = *reinterpret_cast<const float4*>(wnp + 4 * i);
            Wt[sk + 4 * i + 0][se] = (double)a.x + (double)b.x;
            Wt[sk + 4 * i + 1][se] = (double)a.y + (double)b.y;
            Wt[sk + 4 * i + 2][se] = (double)a.z + (double)b.z;
            Wt[sk + 4 * i + 3][se] = (double)a.w + (double)b.w;
        }
        {
            const float* xp = x + (size_t)(t0 + st) * N_EMBED + kc + sx;
            const float4 a = *reinterpret_cast<const float4*>(xp);
            xsd[st][sx + 0] = (double)a.x;
            xsd[st][sx + 1] = (double)a.y;
            xsd[st][sx + 2] = (double)a.z;
            xsd[st][sx + 3] = (double)a.w;
        }
        __syncthreads();
#pragma unroll 4
        for (int kk = 0; kk < 64; kk += 4) {
            const double w0 = Wt[kk + 0][lane];
            const double w1 = Wt[kk + 1][lane];
            const double w2 = Wt[kk + 2][lane];
            const double w3 = Wt[kk + 3][lane];
#pragma unroll
            for (int t = 0; t < 4; ++t) {
                const double2 p = *reinterpret_cast<const double2*>(&xsd[tb + t][kk]);
                const double2 q = *reinterpret_cast<const double2*>(&xsd[tb + t][kk + 2]);
                acc[t] = fma(p.x, w0, acc[t]);
                acc[t] = fma(p.y, w1, acc[t]);
                acc[t] = fma(q.x, w2, acc[t]);
                acc[t] = fma(q.y, w3, acc[t]);
            }
        }
    }

    float* out_router = out;
    float* out_idx    = out + (size_t)n_tokens * N_EXPERTS;
#pragma unroll
    for (int t = 0; t < 4; ++t)
        topk8_write(acc[t] + myb, lane, (size_t)(t0 + tb + t), out_router, out_idx);
}

extern "C" void kernel_launch(void* const* d_in, const int* in_sizes, int n_in,
                              void* d_out, int out_size, void* d_ws, size_t ws_size,
                              hipStream_t stream) {
    const float* x  = (const float*)d_in[0];
    const float* Wl = (const float*)d_in[1];
    const float* bl = (const float*)d_in[2];
    const float* Wn = (const float*)d_in[3];
    const float* bn = (const float*)d_in[4];
    float* out = (float*)d_out;

    int n_tokens = in_sizes[0] / N_EMBED;              // 16384

    const size_t off_wgf   = (size_t)N_EXPERTS * N_EMBED * sizeof(double);  // 1 MB
    const size_t off_flags = off_wgf + (size_t)N_EXPERTS * N_EMBED * sizeof(float);
    const size_t need      = off_flags + (size_t)n_tokens * sizeof(uint32_t);

    if (ws_size >= need) {
        double*   Wp    = (double*)d_ws;
        float*    Wgf   = (float*)((char*)d_ws + off_wgf);
        uint32_t* flags = (uint32_t*)((char*)d_ws + off_flags);

        hipLaunchKernelGGL(combine_w_kernel, dim3((N_EXPERTS * N_EMBED) / 256),
                           dim3(256), 0, stream, Wl, Wn, Wp, Wgf);
        hipLaunchKernelGGL(pass1_kernel, dim3(n_tokens / NT), dim3(1024), 0, stream,
                           x, Wgf, bl, bn, out, flags, n_tokens);
        hipLaunchKernelGGL(pass2_kernel, dim3(n_tokens), dim3(256), 0, stream,
                           x, Wp, bl, bn, flags, out, n_tokens);
    } else {
        hipLaunchKernelGGL(noisy_topk_fallback, dim3(n_tokens / 32), dim3(512), 0, stream,
                           x, Wl, bl, Wn, bn, out, n_tokens);
    }
}